// Round 9
// baseline (52.388 us; speedup 1.0000x reference)
//
#include <hip/hip_runtime.h>
#include <math.h>

// ---------------------------------------------------------------------------
// Att_cov, round 9: r8 skeleton (4 kernels, zero global atomics) with 64KB
// LDS tables (BD_H=1024 is thread-limited at 2 blocks/CU, so 64KB is free):
//  - scatter RANGE_S=16384 f32 (64KB) -> Rs=4 col/row scans (was 7)
//  - histogram RANGE_H=32768 u16-packed (64KB) -> Rh=2 col scans (was 4)
//  - Ch=32 deg chunks (max count 25000 < 65536): pd traffic halved
// Chain: k1{proj || u16-hist} -> k2{dinv || sigmoid} -> k3{scatter} ->
//        k4{fused partial-reduce + double ragged softmax}.
// ws (floats): pa[N] | pb[N] | hbuf[N] (h->g) | dv1[N] | accfb[N] |
//              partial[Cs*N f32]  (aliased first as u16 deg-partial [Ch*N])
// ---------------------------------------------------------------------------

#define RANGE_S 16384
#define RANGE_H 32768
#define BD_H 1024
#define SOFT_LDS_CAP 2048

typedef unsigned short u16t;
typedef unsigned int u32t;

// k1: blocks [0,nodeBlocks) project nodes; blocks [nodeBlocks,+Rh*Ch) histogram.
__global__ __launch_bounds__(BD_H)
void k1_node_hist(const float* __restrict__ x,
                  const float* __restrict__ W_edge,
                  const float* __restrict__ W_gcn,
                  const int* __restrict__ ei,
                  float* __restrict__ pa, float* __restrict__ pb,
                  float* __restrict__ hbuf,
                  u16t* __restrict__ pd,
                  int N, int E, int Ch, int Rh, int CHh, int nodeBlocks, int vec) {
    __shared__ u32t t32[RANGE_H / 2];       // 64KB; aliased as W cache for proj
    const int bid = blockIdx.x, tid = threadIdx.x;
    if (bid < nodeBlocks) {
        float4* Wsh = (float4*)t32;         // [0..15]=Wa [16..31]=Wb [32..47]=Wg
        if (tid < 32) Wsh[tid] = ((const float4*)W_edge)[tid];
        else if (tid < 48) Wsh[tid] = ((const float4*)W_gcn)[tid - 32];
        __syncthreads();
        int lane = tid & 15;
        long long gid = (long long)bid * BD_H + tid;
        int i = (int)(gid >> 4);
        if (i >= N) return;
        float4 v = ((const float4*)(x + (size_t)i * 64))[lane];
        float4 wa = Wsh[lane], wb = Wsh[16 + lane], wg = Wsh[32 + lane];
        float p1 = v.x*wa.x + v.y*wa.y + v.z*wa.z + v.w*wa.w;
        float p2 = v.x*wb.x + v.y*wb.y + v.z*wb.z + v.w*wb.w;
        float p3 = v.x*wg.x + v.y*wg.y + v.z*wg.z + v.w*wg.w;
#pragma unroll
        for (int s = 1; s < 16; s <<= 1) {
            p1 += __shfl_xor(p1, s);
            p2 += __shfl_xor(p2, s);
            p3 += __shfl_xor(p3, s);
        }
        if (lane == 0) {
            pa[i] = p1;
            pb[i] = p2;
            hbuf[i] = p3;
        }
        return;
    }
    const int hb = bid - nodeBlocks;
    const int c = hb / Rh;
    const int r = hb - c * Rh;
    const int lo = r * RANGE_H;
    for (int j = tid; j < RANGE_H / 2; j += BD_H) t32[j] = 0u;
    __syncthreads();
    const int e_lo = c * CHh;
    const int e_hi = (E < e_lo + CHh) ? E : (e_lo + CHh);
    const int* __restrict__ col = ei + E;
    for (int e = e_lo + tid * 4; e < e_hi; e += BD_H * 4) {
        if (vec && e + 3 < e_hi) {
            int4 cc = *(const int4*)(col + e);
            unsigned u;
            u = (unsigned)(cc.x - lo); if (u < RANGE_H) atomicAdd(&t32[u >> 1], 1u << ((u & 1) << 4));
            u = (unsigned)(cc.y - lo); if (u < RANGE_H) atomicAdd(&t32[u >> 1], 1u << ((u & 1) << 4));
            u = (unsigned)(cc.z - lo); if (u < RANGE_H) atomicAdd(&t32[u >> 1], 1u << ((u & 1) << 4));
            u = (unsigned)(cc.w - lo); if (u < RANGE_H) atomicAdd(&t32[u >> 1], 1u << ((u & 1) << 4));
        } else {
            int ee = (e_hi < e + 4) ? e_hi : e + 4;
            for (int q = e; q < ee; ++q) {
                unsigned u = (unsigned)(col[q] - lo);
                if (u < RANGE_H) atomicAdd(&t32[u >> 1], 1u << ((u & 1) << 4));
            }
        }
    }
    __syncthreads();
    const size_t base = (size_t)c * N;
    for (int j = tid; j < RANGE_H; j += BD_H) {
        int node = lo + j;
        if (node < N)
            pd[base + node] = (u16t)(t32[j >> 1] >> ((j & 1) << 4));
    }
}

// k2: blocks [0,dinvBlocks) compute dinv & g from u16 deg-partial; rest sigmoid.
__global__ __launch_bounds__(256)
void k2_dinv_sig(const int* __restrict__ ei,
                 const float* __restrict__ pa, const float* __restrict__ pb,
                 const float* __restrict__ b_edge,
                 const u16t* __restrict__ pd,
                 float* __restrict__ hbuf,       // in: h, out: g = h*dinv
                 float* __restrict__ dv1,
                 float* __restrict__ om, float* __restrict__ os,
                 int N, int E, int Ch, int dinvBlocks, int vec) {
    const int bid = blockIdx.x, tid = threadIdx.x;
    if (bid < dinvBlocks) {
        int i = bid * 256 + tid;
        if (i >= N) return;
        unsigned d0 = 1u, d1 = 0u, d2 = 0u, d3 = 0u;   // self-loop in d0
        int c = 0;
        for (; c + 3 < Ch; c += 4) {
            d0 += pd[(size_t)(c + 0) * N + i];
            d1 += pd[(size_t)(c + 1) * N + i];
            d2 += pd[(size_t)(c + 2) * N + i];
            d3 += pd[(size_t)(c + 3) * N + i];
        }
        for (; c < Ch; ++c) d0 += pd[(size_t)c * N + i];
        float dv = rsqrtf((float)((d0 + d1) + (d2 + d3)));
        hbuf[i] *= dv;
        dv1[i] = dv;
        return;
    }
    int t = (bid - dinvBlocks) * 256 + tid;
    int e0 = t * 4;
    const float b = b_edge[0];
    if (vec && e0 + 3 < E) {
        int4 r = *(const int4*)(ei + e0);
        int4 c = *(const int4*)(ei + E + e0);
        float4 m;
        m.x = 1.f / (1.f + expf(-(pa[r.x] + pb[c.x] + b)));
        m.y = 1.f / (1.f + expf(-(pa[r.y] + pb[c.y] + b)));
        m.z = 1.f / (1.f + expf(-(pa[r.z] + pb[c.z] + b)));
        m.w = 1.f / (1.f + expf(-(pa[r.w] + pb[c.w] + b)));
        *(float4*)(om + e0) = m;
        *(float4*)(os + e0) = make_float4(1.f - m.x, 1.f - m.y, 1.f - m.z, 1.f - m.w);
    } else if (e0 < E) {
        int ee = (E < e0 + 4) ? E : e0 + 4;
        for (int e = e0; e < ee; ++e) {
            float a = 1.f / (1.f + expf(-(pa[ei[e]] + pb[ei[E + e]] + b)));
            om[e] = a; os[e] = 1.f - a;
        }
    }
}

// k3: partitioned f32 scatter, 64KB table.
__global__ __launch_bounds__(BD_H)
void k3_scat(const int* __restrict__ ei,
             const float* __restrict__ g1,
             float* __restrict__ partial,
             int N, int E, int Cs, int Rs, int CHs, int vec) {
    __shared__ float table[RANGE_S];
    const int tid = threadIdx.x;
    const int c = blockIdx.x / Rs;
    const int r = blockIdx.x - c * Rs;
    const int lo = r * RANGE_S;
    for (int j = tid; j < RANGE_S; j += BD_H) table[j] = 0.f;
    __syncthreads();
    const int e_lo = c * CHs;
    const int e_hi = (E < e_lo + CHs) ? E : (e_lo + CHs);
    const int* __restrict__ row = ei;
    const int* __restrict__ col = ei + E;
    for (int e = e_lo + tid * 4; e < e_hi; e += BD_H * 4) {
        if (vec && e + 3 < e_hi) {
            int4 cc = *(const int4*)(col + e);
            int4 rr = *(const int4*)(row + e);
            unsigned u;
            u = (unsigned)(cc.x - lo); if (u < RANGE_S) atomicAdd(&table[u], g1[rr.x]);
            u = (unsigned)(cc.y - lo); if (u < RANGE_S) atomicAdd(&table[u], g1[rr.y]);
            u = (unsigned)(cc.z - lo); if (u < RANGE_S) atomicAdd(&table[u], g1[rr.z]);
            u = (unsigned)(cc.w - lo); if (u < RANGE_S) atomicAdd(&table[u], g1[rr.w]);
        } else {
            int ee = (e_hi < e + 4) ? e_hi : e + 4;
            for (int q = e; q < ee; ++q) {
                unsigned u = (unsigned)(col[q] - lo);
                if (u < RANGE_S) atomicAdd(&table[u], g1[row[q]]);
            }
        }
    }
    __syncthreads();
    const size_t base = (size_t)c * N;
    for (int j = tid; j < RANGE_S; j += BD_H) {
        int node = lo + j;
        if (node < N) partial[base + node] = table[j];
    }
}

// k4: one block/graph; fused partial-reduce + two chained ragged softmaxes.
__global__ __launch_bounds__(128)
void k4_softmax(const float* __restrict__ hbuf,   // g
                const float* __restrict__ dv1,
                const float* __restrict__ partial,
                float* __restrict__ accfb,
                const int* __restrict__ split_n,
                float* __restrict__ out_m, float* __restrict__ out_s,
                int N, int Cs) {
    __shared__ float red[128];
    __shared__ int ired[128];
    __shared__ int sh_off;
    __shared__ float sv[SOFT_LDS_CAP];
    const int g = blockIdx.x;
    const int tid = threadIdx.x;
    const int BD = blockDim.x;

    int part = 0;
    for (int j = tid; j < g; j += BD) part += split_n[j];
    ired[tid] = part; __syncthreads();
    for (int s = 64; s > 0; s >>= 1) {
        if (tid < s) ired[tid] += ired[tid + s];
        __syncthreads();
    }
    if (tid == 0) sh_off = ired[0];
    __syncthreads();
    const int off = sh_off;
    const int cnt = split_n[g];
    const bool fits = (cnt <= SOFT_LDS_CAP);

    for (int j = tid; j < cnt; j += BD) {
        int node = off + j;
        float s0 = hbuf[node], s1 = 0.f, s2 = 0.f, s3 = 0.f;
        int c = 0;
        for (; c + 3 < Cs; c += 4) {
            s0 += partial[(size_t)(c + 0) * N + node];
            s1 += partial[(size_t)(c + 1) * N + node];
            s2 += partial[(size_t)(c + 2) * N + node];
            s3 += partial[(size_t)(c + 3) * N + node];
        }
        for (; c < Cs; ++c) s0 += partial[(size_t)c * N + node];
        float a = dv1[node] * ((s0 + s1) + (s2 + s3));
        if (fits) sv[j] = a; else accfb[node] = a;
    }
    __syncthreads();

    // softmax #1
    float mx = -INFINITY;
    for (int j = tid; j < cnt; j += BD) mx = fmaxf(mx, fits ? sv[j] : accfb[off + j]);
    red[tid] = mx; __syncthreads();
    for (int s = 64; s > 0; s >>= 1) {
        if (tid < s) red[tid] = fmaxf(red[tid], red[tid + s]);
        __syncthreads();
    }
    mx = red[0]; __syncthreads();
    float sum = 0.f;
    for (int j = tid; j < cnt; j += BD) sum += expf((fits ? sv[j] : accfb[off + j]) - mx);
    red[tid] = sum; __syncthreads();
    for (int s = 64; s > 0; s >>= 1) {
        if (tid < s) red[tid] += red[tid + s];
        __syncthreads();
    }
    const float inv1 = 1.0f / red[0]; __syncthreads();
    for (int j = tid; j < cnt; j += BD) {
        float mv = expf((fits ? sv[j] : accfb[off + j]) - mx) * inv1;
        out_m[off + j] = mv;
        if (fits) sv[j] = mv;
    }
    __syncthreads();

    // softmax #2 over (1 - m)
    float mx2 = -INFINITY;
    for (int j = tid; j < cnt; j += BD)
        mx2 = fmaxf(mx2, 1.0f - (fits ? sv[j] : out_m[off + j]));
    red[tid] = mx2; __syncthreads();
    for (int s = 64; s > 0; s >>= 1) {
        if (tid < s) red[tid] = fmaxf(red[tid], red[tid + s]);
        __syncthreads();
    }
    mx2 = red[0]; __syncthreads();
    float sum2 = 0.f;
    for (int j = tid; j < cnt; j += BD)
        sum2 += expf(1.0f - (fits ? sv[j] : out_m[off + j]) - mx2);
    red[tid] = sum2; __syncthreads();
    for (int s = 64; s > 0; s >>= 1) {
        if (tid < s) red[tid] += red[tid + s];
        __syncthreads();
    }
    const float inv2 = 1.0f / red[0]; __syncthreads();
    for (int j = tid; j < cnt; j += BD)
        out_s[off + j] = expf(1.0f - (fits ? sv[j] : out_m[off + j]) - mx2) * inv2;
}

extern "C" void kernel_launch(void* const* d_in, const int* in_sizes, int n_in,
                              void* d_out, int out_size, void* d_ws, size_t ws_size,
                              hipStream_t stream) {
    const float* x      = (const float*)d_in[0];
    const int*   ei     = (const int*)d_in[1];
    const int*   splitn = (const int*)d_in[2];
    const float* W_edge = (const float*)d_in[3];
    const float* b_edge = (const float*)d_in[4];
    const float* W_gcn  = (const float*)d_in[5];

    const int N = in_sizes[0] / 64;
    const int E = in_sizes[1] / 2;
    const int G = in_sizes[2];

    float* out = (float*)d_out;
    float* edge_m = out;
    float* edge_s = out + E;
    float* node_m = out + 2LL * E;
    float* node_s = out + 2LL * E + N;

    int Cs = 64;
    while (Cs > 2 && (size_t)(5 + Cs) * N * sizeof(float) > ws_size) Cs >>= 1;
    int Ch = 32;
    // per-chunk u16 count safety: ceil(E/Ch) must stay < 65536
    while ((E + Ch - 1) / Ch >= 65536) Ch <<= 1;
    const int Rs = (N + RANGE_S - 1) / RANGE_S;
    const int Rh = (N + RANGE_H - 1) / RANGE_H;
    const int CHs = (((E + Cs - 1) / Cs) + 3) & ~3;
    const int CHh = (((E + Ch - 1) / Ch) + 3) & ~3;
    const int vec = ((E & 3) == 0) ? 1 : 0;

    float* pa      = (float*)d_ws;
    float* pb      = pa + N;
    float* hbuf    = pb + N;
    float* dv1     = hbuf + N;
    float* accfb   = dv1 + N;
    float* partial = accfb + N;              // f32 scatter partial (Cs*N)
    u16t*  pd      = (u16t*)partial;         // aliased u16 deg partial (Ch*N)

    const int nodeBlocks = (int)(((long long)N * 16 + BD_H - 1) / BD_H);
    const int dinvBlocks = (N + 255) / 256;
    const int sigBlocks  = ((E + 3) / 4 + 255) / 256;

    k1_node_hist<<<nodeBlocks + Rh * Ch, BD_H, 0, stream>>>(
        x, W_edge, W_gcn, ei, pa, pb, hbuf, pd, N, E, Ch, Rh, CHh, nodeBlocks, vec);
    k2_dinv_sig<<<dinvBlocks + sigBlocks, 256, 0, stream>>>(
        ei, pa, pb, b_edge, pd, hbuf, dv1, edge_m, edge_s, N, E, Ch, dinvBlocks, vec);
    k3_scat<<<Rs * Cs, BD_H, 0, stream>>>(ei, hbuf, partial, N, E, Cs, Rs, CHs, vec);
    k4_softmax<<<G, 128, 0, stream>>>(hbuf, dv1, partial, accfb, splitn,
                                      node_m, node_s, N, Cs);
}

// Round 10
// 49.835 us; speedup vs baseline: 1.0512x; 1.0512x over previous
//
#include <hip/hip_runtime.h>
#include <math.h>

// ---------------------------------------------------------------------------
// Att_cov, round 10: rebalanced 4-launch chain, zero global atomics.
//  k1: u16 degree histogram (128 blocks FIRST) || node projections
//  k2: dinv only (tiny)
//  k3: GCN scatter (256 blocks FIRST) || edge sigmoid (concurrent, dep-free)
//  k4: per-graph fused partial-reduce + double ragged softmax
// Histogram: RANGE_H=32768 u16-packed in 64KB LDS, Ch=64 chunks -> Rh=2
//   col scans, 128 blocks (vs r9's 64 — occupancy restored).
// Scatter: RANGE_S=16384 f32 (64KB), Cs=64 -> Rs=4 scans, 256 blocks.
// ws (floats): pa[N] | pb[N] | hbuf[N] (h->g) | dv1[N] | accfb[N] |
//              partial[Cs*N f32]  (aliased first as u16 deg-partial [Ch*N])
// ---------------------------------------------------------------------------

#define RANGE_S 16384
#define RANGE_H 32768
#define BD_H 1024
#define SOFT_LDS_CAP 2048

typedef unsigned short u16t;
typedef unsigned int u32t;

// k1: blocks [0,histBlocks) histogram; rest project nodes.
__global__ __launch_bounds__(BD_H)
void k1_hist_node(const float* __restrict__ x,
                  const float* __restrict__ W_edge,
                  const float* __restrict__ W_gcn,
                  const int* __restrict__ ei,
                  float* __restrict__ pa, float* __restrict__ pb,
                  float* __restrict__ hbuf,
                  u16t* __restrict__ pd,
                  int N, int E, int Ch, int Rh, int CHh, int histBlocks, int vec) {
    __shared__ u32t t32[RANGE_H / 2];       // 64KB; aliased as W cache for proj
    const int bid = blockIdx.x, tid = threadIdx.x;
    if (bid >= histBlocks) {
        float4* Wsh = (float4*)t32;         // [0..15]=Wa [16..31]=Wb [32..47]=Wg
        if (tid < 32) Wsh[tid] = ((const float4*)W_edge)[tid];
        else if (tid < 48) Wsh[tid] = ((const float4*)W_gcn)[tid - 32];
        __syncthreads();
        int lane = tid & 15;
        long long gid = (long long)(bid - histBlocks) * BD_H + tid;
        int i = (int)(gid >> 4);
        if (i >= N) return;
        float4 v = ((const float4*)(x + (size_t)i * 64))[lane];
        float4 wa = Wsh[lane], wb = Wsh[16 + lane], wg = Wsh[32 + lane];
        float p1 = v.x*wa.x + v.y*wa.y + v.z*wa.z + v.w*wa.w;
        float p2 = v.x*wb.x + v.y*wb.y + v.z*wb.z + v.w*wb.w;
        float p3 = v.x*wg.x + v.y*wg.y + v.z*wg.z + v.w*wg.w;
#pragma unroll
        for (int s = 1; s < 16; s <<= 1) {
            p1 += __shfl_xor(p1, s);
            p2 += __shfl_xor(p2, s);
            p3 += __shfl_xor(p3, s);
        }
        if (lane == 0) {
            pa[i] = p1;
            pb[i] = p2;
            hbuf[i] = p3;
        }
        return;
    }
    const int c = bid / Rh;
    const int r = bid - c * Rh;
    const int lo = r * RANGE_H;
    for (int j = tid; j < RANGE_H / 2; j += BD_H) t32[j] = 0u;
    __syncthreads();
    const int e_lo = c * CHh;
    const int e_hi = (E < e_lo + CHh) ? E : (e_lo + CHh);
    const int* __restrict__ col = ei + E;
    for (int e = e_lo + tid * 4; e < e_hi; e += BD_H * 4) {
        if (vec && e + 3 < e_hi) {
            int4 cc = *(const int4*)(col + e);
            unsigned u;
            u = (unsigned)(cc.x - lo); if (u < RANGE_H) atomicAdd(&t32[u >> 1], 1u << ((u & 1) << 4));
            u = (unsigned)(cc.y - lo); if (u < RANGE_H) atomicAdd(&t32[u >> 1], 1u << ((u & 1) << 4));
            u = (unsigned)(cc.z - lo); if (u < RANGE_H) atomicAdd(&t32[u >> 1], 1u << ((u & 1) << 4));
            u = (unsigned)(cc.w - lo); if (u < RANGE_H) atomicAdd(&t32[u >> 1], 1u << ((u & 1) << 4));
        } else {
            int ee = (e_hi < e + 4) ? e_hi : e + 4;
            for (int q = e; q < ee; ++q) {
                unsigned u = (unsigned)(col[q] - lo);
                if (u < RANGE_H) atomicAdd(&t32[u >> 1], 1u << ((u & 1) << 4));
            }
        }
    }
    __syncthreads();
    const size_t base = (size_t)c * N;
    for (int j = tid; j < RANGE_H; j += BD_H) {
        int node = lo + j;
        if (node < N)
            pd[base + node] = (u16t)(t32[j >> 1] >> ((j & 1) << 4));
    }
}

// k2: dinv only.
__global__ __launch_bounds__(256)
void k2_dinv(const u16t* __restrict__ pd,
             float* __restrict__ hbuf,       // in: h, out: g = h*dinv
             float* __restrict__ dv1,
             int N, int Ch) {
    int i = blockIdx.x * 256 + threadIdx.x;
    if (i >= N) return;
    unsigned d0 = 1u, d1 = 0u, d2 = 0u, d3 = 0u;   // self-loop in d0
    int c = 0;
    for (; c + 3 < Ch; c += 4) {
        d0 += pd[(size_t)(c + 0) * N + i];
        d1 += pd[(size_t)(c + 1) * N + i];
        d2 += pd[(size_t)(c + 2) * N + i];
        d3 += pd[(size_t)(c + 3) * N + i];
    }
    for (; c < Ch; ++c) d0 += pd[(size_t)c * N + i];
    float dv = rsqrtf((float)((d0 + d1) + (d2 + d3)));
    hbuf[i] *= dv;
    dv1[i] = dv;
}

// k3: blocks [0,scatBlocks) partitioned scatter; rest edge sigmoid
// (sigmoid depends only on k1 — runs concurrently with scatter).
__global__ __launch_bounds__(BD_H)
void k3_scat_sig(const int* __restrict__ ei,
                 const float* __restrict__ g1,
                 const float* __restrict__ pa, const float* __restrict__ pb,
                 const float* __restrict__ b_edge,
                 float* __restrict__ partial,
                 float* __restrict__ om, float* __restrict__ os,
                 int N, int E, int Cs, int Rs, int CHs, int scatBlocks, int vec) {
    const int bid = blockIdx.x, tid = threadIdx.x;
    if (bid >= scatBlocks) {
        int t = (bid - scatBlocks) * BD_H + tid;
        int e0 = t * 4;
        const float b = b_edge[0];
        if (vec && e0 + 3 < E) {
            int4 r = *(const int4*)(ei + e0);
            int4 c = *(const int4*)(ei + E + e0);
            float4 m;
            m.x = 1.f / (1.f + expf(-(pa[r.x] + pb[c.x] + b)));
            m.y = 1.f / (1.f + expf(-(pa[r.y] + pb[c.y] + b)));
            m.z = 1.f / (1.f + expf(-(pa[r.z] + pb[c.z] + b)));
            m.w = 1.f / (1.f + expf(-(pa[r.w] + pb[c.w] + b)));
            *(float4*)(om + e0) = m;
            *(float4*)(os + e0) = make_float4(1.f - m.x, 1.f - m.y, 1.f - m.z, 1.f - m.w);
        } else if (e0 < E) {
            int ee = (E < e0 + 4) ? E : e0 + 4;
            for (int e = e0; e < ee; ++e) {
                float a = 1.f / (1.f + expf(-(pa[ei[e]] + pb[ei[E + e]] + b)));
                om[e] = a; os[e] = 1.f - a;
            }
        }
        return;
    }
    __shared__ float table[RANGE_S];
    const int c = bid / Rs;
    const int r = bid - c * Rs;
    const int lo = r * RANGE_S;
    for (int j = tid; j < RANGE_S; j += BD_H) table[j] = 0.f;
    __syncthreads();
    const int e_lo = c * CHs;
    const int e_hi = (E < e_lo + CHs) ? E : (e_lo + CHs);
    const int* __restrict__ row = ei;
    const int* __restrict__ col = ei + E;
    for (int e = e_lo + tid * 4; e < e_hi; e += BD_H * 4) {
        if (vec && e + 3 < e_hi) {
            int4 cc = *(const int4*)(col + e);
            int4 rr = *(const int4*)(row + e);
            unsigned u;
            u = (unsigned)(cc.x - lo); if (u < RANGE_S) atomicAdd(&table[u], g1[rr.x]);
            u = (unsigned)(cc.y - lo); if (u < RANGE_S) atomicAdd(&table[u], g1[rr.y]);
            u = (unsigned)(cc.z - lo); if (u < RANGE_S) atomicAdd(&table[u], g1[rr.z]);
            u = (unsigned)(cc.w - lo); if (u < RANGE_S) atomicAdd(&table[u], g1[rr.w]);
        } else {
            int ee = (e_hi < e + 4) ? e_hi : e + 4;
            for (int q = e; q < ee; ++q) {
                unsigned u = (unsigned)(col[q] - lo);
                if (u < RANGE_S) atomicAdd(&table[u], g1[row[q]]);
            }
        }
    }
    __syncthreads();
    const size_t base = (size_t)c * N;
    for (int j = tid; j < RANGE_S; j += BD_H) {
        int node = lo + j;
        if (node < N) partial[base + node] = table[j];
    }
}

// k4: one block/graph; fused partial-reduce + two chained ragged softmaxes.
__global__ __launch_bounds__(128)
void k4_softmax(const float* __restrict__ hbuf,   // g
                const float* __restrict__ dv1,
                const float* __restrict__ partial,
                float* __restrict__ accfb,
                const int* __restrict__ split_n,
                float* __restrict__ out_m, float* __restrict__ out_s,
                int N, int Cs) {
    __shared__ float red[128];
    __shared__ int ired[128];
    __shared__ int sh_off;
    __shared__ float sv[SOFT_LDS_CAP];
    const int g = blockIdx.x;
    const int tid = threadIdx.x;
    const int BD = blockDim.x;

    int part = 0;
    for (int j = tid; j < g; j += BD) part += split_n[j];
    ired[tid] = part; __syncthreads();
    for (int s = 64; s > 0; s >>= 1) {
        if (tid < s) ired[tid] += ired[tid + s];
        __syncthreads();
    }
    if (tid == 0) sh_off = ired[0];
    __syncthreads();
    const int off = sh_off;
    const int cnt = split_n[g];
    const bool fits = (cnt <= SOFT_LDS_CAP);

    for (int j = tid; j < cnt; j += BD) {
        int node = off + j;
        float s0 = hbuf[node], s1 = 0.f, s2 = 0.f, s3 = 0.f;
        int c = 0;
        for (; c + 3 < Cs; c += 4) {
            s0 += partial[(size_t)(c + 0) * N + node];
            s1 += partial[(size_t)(c + 1) * N + node];
            s2 += partial[(size_t)(c + 2) * N + node];
            s3 += partial[(size_t)(c + 3) * N + node];
        }
        for (; c < Cs; ++c) s0 += partial[(size_t)c * N + node];
        float a = dv1[node] * ((s0 + s1) + (s2 + s3));
        if (fits) sv[j] = a; else accfb[node] = a;
    }
    __syncthreads();

    // softmax #1
    float mx = -INFINITY;
    for (int j = tid; j < cnt; j += BD) mx = fmaxf(mx, fits ? sv[j] : accfb[off + j]);
    red[tid] = mx; __syncthreads();
    for (int s = 64; s > 0; s >>= 1) {
        if (tid < s) red[tid] = fmaxf(red[tid], red[tid + s]);
        __syncthreads();
    }
    mx = red[0]; __syncthreads();
    float sum = 0.f;
    for (int j = tid; j < cnt; j += BD) sum += expf((fits ? sv[j] : accfb[off + j]) - mx);
    red[tid] = sum; __syncthreads();
    for (int s = 64; s > 0; s >>= 1) {
        if (tid < s) red[tid] += red[tid + s];
        __syncthreads();
    }
    const float inv1 = 1.0f / red[0]; __syncthreads();
    for (int j = tid; j < cnt; j += BD) {
        float mv = expf((fits ? sv[j] : accfb[off + j]) - mx) * inv1;
        out_m[off + j] = mv;
        if (fits) sv[j] = mv;
    }
    __syncthreads();

    // softmax #2 over (1 - m)
    float mx2 = -INFINITY;
    for (int j = tid; j < cnt; j += BD)
        mx2 = fmaxf(mx2, 1.0f - (fits ? sv[j] : out_m[off + j]));
    red[tid] = mx2; __syncthreads();
    for (int s = 64; s > 0; s >>= 1) {
        if (tid < s) red[tid] = fmaxf(red[tid], red[tid + s]);
        __syncthreads();
    }
    mx2 = red[0]; __syncthreads();
    float sum2 = 0.f;
    for (int j = tid; j < cnt; j += BD)
        sum2 += expf(1.0f - (fits ? sv[j] : out_m[off + j]) - mx2);
    red[tid] = sum2; __syncthreads();
    for (int s = 64; s > 0; s >>= 1) {
        if (tid < s) red[tid] += red[tid + s];
        __syncthreads();
    }
    const float inv2 = 1.0f / red[0]; __syncthreads();
    for (int j = tid; j < cnt; j += BD)
        out_s[off + j] = expf(1.0f - (fits ? sv[j] : out_m[off + j]) - mx2) * inv2;
}

extern "C" void kernel_launch(void* const* d_in, const int* in_sizes, int n_in,
                              void* d_out, int out_size, void* d_ws, size_t ws_size,
                              hipStream_t stream) {
    const float* x      = (const float*)d_in[0];
    const int*   ei     = (const int*)d_in[1];
    const int*   splitn = (const int*)d_in[2];
    const float* W_edge = (const float*)d_in[3];
    const float* b_edge = (const float*)d_in[4];
    const float* W_gcn  = (const float*)d_in[5];

    const int N = in_sizes[0] / 64;
    const int E = in_sizes[1] / 2;
    const int G = in_sizes[2];

    float* out = (float*)d_out;
    float* edge_m = out;
    float* edge_s = out + E;
    float* node_m = out + 2LL * E;
    float* node_s = out + 2LL * E + N;

    int Cs = 64;
    while (Cs > 2 && (size_t)(5 + Cs) * N * sizeof(float) > ws_size) Cs >>= 1;
    int Ch = 64;
    while ((E + Ch - 1) / Ch >= 65536) Ch <<= 1;   // u16 per-chunk count safety
    const int Rs = (N + RANGE_S - 1) / RANGE_S;
    const int Rh = (N + RANGE_H - 1) / RANGE_H;
    const int CHs = (((E + Cs - 1) / Cs) + 3) & ~3;
    const int CHh = (((E + Ch - 1) / Ch) + 3) & ~3;
    const int vec = ((E & 3) == 0) ? 1 : 0;

    float* pa      = (float*)d_ws;
    float* pb      = pa + N;
    float* hbuf    = pb + N;
    float* dv1     = hbuf + N;
    float* accfb   = dv1 + N;
    float* partial = accfb + N;              // f32 scatter partial (Cs*N)
    u16t*  pd      = (u16t*)partial;         // aliased u16 deg partial (Ch*N)

    const int histBlocks = Rh * Ch;
    const int projBlocks = (int)(((long long)N * 16 + BD_H - 1) / BD_H);
    const int scatBlocks = Rs * Cs;
    const int sigBlocks  = (int)(((long long)E / 4 + BD_H - 1) / BD_H) + ((E & 3) ? 1 : 0);
    const int dinvBlocks = (N + 255) / 256;

    k1_hist_node<<<histBlocks + projBlocks, BD_H, 0, stream>>>(
        x, W_edge, W_gcn, ei, pa, pb, hbuf, pd, N, E, Ch, Rh, CHh, histBlocks, vec);
    k2_dinv<<<dinvBlocks, 256, 0, stream>>>(pd, hbuf, dv1, N, Ch);
    k3_scat_sig<<<scatBlocks + sigBlocks, BD_H, 0, stream>>>(
        ei, hbuf, pa, pb, b_edge, partial, edge_m, edge_s,
        N, E, Cs, Rs, CHs, scatBlocks, vec);
    k4_softmax<<<G, 128, 0, stream>>>(hbuf, dv1, partial, accfb, splitn,
                                      node_m, node_s, N, Cs);
}